// Round 2
// baseline (334.100 us; speedup 1.0000x reference)
//
#include <hip/hip_runtime.h>
#include <math.h>

// Fused Bayesian-logistic-regression sampling:
//   out[i,s] = sigmoid( sqrt(sum_j X_ij^2 * exp(lv_j)) * z_s + sum_j X_ij * mu_j )
//
// Memory-bound: 128 MB read (X) + 256 MB write (out) -> ~61 us HBM floor.
// R2 changes vs R1: 4 rows per 16-lane group (4x in-flight load bytes, 4x
// amortized weight setup), nontemporal load/store on the touch-once streams,
// sigmoid = rcp(1 + exp2(t * -log2e)) -> 2 trans + 2 VALU per output.

typedef float f4 __attribute__((ext_vector_type(4)));

__device__ __forceinline__ f4 sigmoid4(float s2, float m2, f4 zz) {
    // computes sigmoid(stdv*z + mean) given s2 = -stdv*log2e, m2 = -mean*log2e
    f4 r;
    r.x = __builtin_amdgcn_rcpf(1.0f + __builtin_amdgcn_exp2f(fmaf(zz.x, s2, m2)));
    r.y = __builtin_amdgcn_rcpf(1.0f + __builtin_amdgcn_exp2f(fmaf(zz.y, s2, m2)));
    r.z = __builtin_amdgcn_rcpf(1.0f + __builtin_amdgcn_exp2f(fmaf(zz.z, s2, m2)));
    r.w = __builtin_amdgcn_rcpf(1.0f + __builtin_amdgcn_exp2f(fmaf(zz.w, s2, m2)));
    return r;
}

__global__ __launch_bounds__(256) void logreg_sample_kernel(
    const float* __restrict__ X,
    const float* __restrict__ w_mu,
    const float* __restrict__ w_lv,
    const float* __restrict__ z,
    float* __restrict__ out,
    int n_rows)
{
    const int tid = blockIdx.x * blockDim.x + threadIdx.x;
    const int grp = tid >> 4;        // 16-lane group
    const int l   = tid & 15;
    const int r0  = grp * 4;         // 4 rows per group
    if (r0 >= n_rows) return;

    // Row-invariant per-lane constants (columns [4l, 4l+4)).
    const f4 mu4 = ((const f4*)w_mu)[l];
    const f4 lv4 = ((const f4*)w_lv)[l];
    f4 ev4;
    ev4.x = __expf(lv4.x); ev4.y = __expf(lv4.y);
    ev4.z = __expf(lv4.z); ev4.w = __expf(lv4.w);
    const f4 z0 = ((const f4*)z)[l];        // samples [4l, 4l+4)
    const f4 z1 = ((const f4*)z)[16 + l];   // samples [64+4l, ...)

    const f4* X4 = (const f4*)X;
    const int nfull = (r0 + 4 <= n_rows) ? 4 : (n_rows - r0);

    if (__builtin_expect(nfull == 4, 1)) {
        // 4 independent nontemporal loads -> 4 KB/wave in flight.
        f4 x[4];
        #pragma unroll
        for (int j = 0; j < 4; ++j)
            x[j] = __builtin_nontemporal_load(&X4[(size_t)(r0 + j) * 16 + l]);

        float a[4], b[4];
        #pragma unroll
        for (int j = 0; j < 4; ++j) {
            a[j] = x[j].x * mu4.x + x[j].y * mu4.y + x[j].z * mu4.z + x[j].w * mu4.w;
            b[j] = x[j].x * x[j].x * ev4.x + x[j].y * x[j].y * ev4.y
                 + x[j].z * x[j].z * ev4.z + x[j].w * x[j].w * ev4.w;
        }

        // Butterfly across the aligned 16-lane group (lowers to DPP/swizzle).
        #pragma unroll
        for (int m = 1; m < 16; m <<= 1) {
            #pragma unroll
            for (int j = 0; j < 4; ++j) {
                a[j] += __shfl_xor(a[j], m, 64);
                b[j] += __shfl_xor(b[j], m, 64);
            }
        }

        const float NEG_LOG2E = -1.4426950408889634f;
        #pragma unroll
        for (int j = 0; j < 4; ++j) {
            const float s2 = sqrtf(b[j]) * NEG_LOG2E;
            const float m2 = a[j] * NEG_LOG2E;
            f4* orow = (f4*)(out + (size_t)(r0 + j) * 128);
            __builtin_nontemporal_store(sigmoid4(s2, m2, z0), &orow[l]);
            __builtin_nontemporal_store(sigmoid4(s2, m2, z1), &orow[16 + l]);
        }
    } else {
        // Tail (n_rows % 4 != 0 safety; unused for N=500000).
        for (int j = 0; j < nfull; ++j) {
            f4 x = X4[(size_t)(r0 + j) * 16 + l];
            float a = x.x * mu4.x + x.y * mu4.y + x.z * mu4.z + x.w * mu4.w;
            float b = x.x * x.x * ev4.x + x.y * x.y * ev4.y
                    + x.z * x.z * ev4.z + x.w * x.w * ev4.w;
            for (int m = 1; m < 16; m <<= 1) {
                a += __shfl_xor(a, m, 64);
                b += __shfl_xor(b, m, 64);
            }
            const float NEG_LOG2E = -1.4426950408889634f;
            const float s2 = sqrtf(b) * NEG_LOG2E;
            const float m2 = a * NEG_LOG2E;
            f4* orow = (f4*)(out + (size_t)(r0 + j) * 128);
            __builtin_nontemporal_store(sigmoid4(s2, m2, z0), &orow[l]);
            __builtin_nontemporal_store(sigmoid4(s2, m2, z1), &orow[16 + l]);
        }
    }
}

extern "C" void kernel_launch(void* const* d_in, const int* in_sizes, int n_in,
                              void* d_out, int out_size, void* d_ws, size_t ws_size,
                              hipStream_t stream) {
    const float* X    = (const float*)d_in[0];
    const float* w_mu = (const float*)d_in[1];
    const float* w_lv = (const float*)d_in[2];
    const float* z    = (const float*)d_in[3];
    float* out = (float*)d_out;

    const int n_rows   = in_sizes[0] / 64;            // 500000
    const int n_groups = (n_rows + 3) / 4;            // 4 rows per 16-lane group
    const int threads  = n_groups * 16;
    const int blocks   = (threads + 255) / 256;

    logreg_sample_kernel<<<blocks, 256, 0, stream>>>(X, w_mu, w_lv, z, out, n_rows);
}